// Round 1
// baseline (368.430 us; speedup 1.0000x reference)
//
#include <hip/hip_runtime.h>
#include <hip/hip_bf16.h>

#define T_ 4
#define B_ 2
#define CK 256
#define CV 512
#define HH 96
#define WW 96
#define NPIX (HH*WW)   // 9216
#define M_ 144         // T_*6*6
#define MP 160         // M_ padded to multiple of 32 for K-loop

typedef __attribute__((ext_vector_type(8))) short short8;
typedef __attribute__((ext_vector_type(4))) float floatx4;

__device__ __forceinline__ unsigned short f2bf(float f) {
    unsigned int u = __float_as_uint(f);
    u += 0x7FFFu + ((u >> 16) & 1u);   // RNE
    return (unsigned short)(u >> 16);
}

// ---------------------------------------------------------------------------
// K1: pool [*,96,96] planes into 50 scale-position means (scales 1,2,3,6).
// One block per (t,b,c) plane; 36 cell means of 16x16 cells, then derive.
// ---------------------------------------------------------------------------
__global__ __launch_bounds__(256) void pool_kernel(
        const float* __restrict__ keys, const float* __restrict__ vals,
        float* __restrict__ pooledK, float* __restrict__ pooledV) {
    int pid = blockIdx.x;
    const float* src; float* dst;
    if (pid < T_*B_*CK) { src = keys + (size_t)pid * NPIX; dst = pooledK + (size_t)pid * 50; }
    else { int p = pid - T_*B_*CK; src = vals + (size_t)p * NPIX; dst = pooledV + (size_t)p * 50; }

    __shared__ float cm[36];
    int tid = threadIdx.x;
    int wv = tid >> 6, lane = tid & 63;
    int r = lane >> 2, c4 = lane & 3;
    #pragma unroll
    for (int g = 0; g < 9; ++g) {
        int cell = g*4 + wv;
        int cr = cell / 6, cc = cell % 6;
        const float4 v = *reinterpret_cast<const float4*>(src + (cr*16 + r)*WW + cc*16 + c4*4);
        float s = v.x + v.y + v.z + v.w;
        #pragma unroll
        for (int m = 1; m < 64; m <<= 1) s += __shfl_xor(s, m);
        if (lane == 0) cm[cell] = s * (1.0f/256.0f);
    }
    __syncthreads();
    if (tid < 50) {
        float v;
        if (tid == 0) {                    // s=1
            float a = 0.f;
            #pragma unroll
            for (int i = 0; i < 36; ++i) a += cm[i];
            v = a * (1.0f/36.0f);
        } else if (tid < 5) {              // s=2: 3x3 groups of cells
            int k = tid - 1; int i = k >> 1, j = k & 1;
            float a = 0.f;
            for (int di = 0; di < 3; ++di)
                for (int dj = 0; dj < 3; ++dj) a += cm[(i*3+di)*6 + (j*3+dj)];
            v = a * (1.0f/9.0f);
        } else if (tid < 14) {             // s=3: 2x2 groups
            int k = tid - 5; int i = k / 3, j = k % 3;
            float a = 0.f;
            for (int di = 0; di < 2; ++di)
                for (int dj = 0; dj < 2; ++dj) a += cm[(i*2+di)*6 + (j*2+dj)];
            v = a * 0.25f;
        } else {                           // s=6
            v = cm[tid - 14];
        }
        dst[tid] = v;
    }
}

// ---------------------------------------------------------------------------
// K2: per-frame/per-scale 1x1 conv + bias + relu. One wave per output elem.
// convK layout [t][b][pos(50)][co(64)], convV [t][b][pos][co(128)].
// ---------------------------------------------------------------------------
__global__ __launch_bounds__(256) void conv_kernel(
        const float* __restrict__ pooledK, const float* __restrict__ pooledV,
        const float* __restrict__ key_w, const float* __restrict__ key_b,
        const float* __restrict__ val_w, const float* __restrict__ val_b,
        float* __restrict__ convK, float* __restrict__ convV) {
    int gid = blockIdx.x * 4 + (threadIdx.x >> 6);
    int lane = threadIdx.x & 63;
    const int EK = T_*B_*50*64;   // 25600
    float acc = 0.f;
    if (gid < EK) {
        int co = gid & 63;
        int pos = (gid >> 6) % 50;
        int tb = gid / (64*50);
        int b = tb & 1, t = tb >> 1;
        int si = (pos == 0) ? 0 : (pos < 5 ? 1 : (pos < 14 ? 2 : 3));
        const float* wrow = key_w + (size_t)((t*4 + si)*64 + co) * CK;
        const float* prow = pooledK + (size_t)((t*B_ + b)*CK) * 50 + pos;
        #pragma unroll
        for (int k = 0; k < 4; ++k) {
            int c = lane + 64*k;
            acc += wrow[c] * prow[(size_t)c * 50];
        }
        #pragma unroll
        for (int m = 1; m < 64; m <<= 1) acc += __shfl_xor(acc, m);
        if (lane == 0) convK[gid] = fmaxf(acc + key_b[(t*4 + si)*64 + co], 0.f);
    } else {
        int g2 = gid - EK;
        int co = g2 & 127;
        int pos = (g2 >> 7) % 50;
        int tb = g2 / (128*50);
        int b = tb & 1, t = tb >> 1;
        int si = (pos == 0) ? 0 : (pos < 5 ? 1 : (pos < 14 ? 2 : 3));
        const float* wrow = val_w + (size_t)((t*4 + si)*128 + co) * CV;
        const float* prow = pooledV + (size_t)((t*B_ + b)*CV) * 50 + pos;
        #pragma unroll
        for (int k = 0; k < 8; ++k) {
            int c = lane + 64*k;
            acc += wrow[c] * prow[(size_t)c * 50];
        }
        #pragma unroll
        for (int m = 1; m < 64; m <<= 1) acc += __shfl_xor(acc, m);
        if (lane == 0) convV[g2] = fmaxf(acc + val_b[(t*4 + si)*128 + co], 0.f);
    }
}

// ---------------------------------------------------------------------------
// K3: bilinear upsample (align_corners=False, jax.image.resize semantics with
// boundary re-normalization) + pack to bf16:
//   mk [b][m=144][c=256], mv [b][cv=512][mp=160] (m 144..159 zeroed).
// ---------------------------------------------------------------------------
__device__ const int   UP_P0[4][6] = {{0,0,0,0,0,0},{0,0,0,0,1,1},{0,0,0,1,1,2},{0,1,2,3,4,5}};
__device__ const int   UP_P1[4][6] = {{0,0,0,0,0,0},{0,0,1,1,1,1},{0,1,1,2,2,2},{0,1,2,3,4,5}};
__device__ const float UP_W0[4][6] = {{1,1,1,1,1,1},
                                      {1,1,0.66666669f,0.33333334f,1,1},
                                      {1,0.75f,0.25f,0.75f,0.25f,1},
                                      {1,1,1,1,1,1}};
__device__ const float UP_W1[4][6] = {{0,0,0,0,0,0},
                                      {0,0,0.33333334f,0.66666669f,0,0},
                                      {0,0.25f,0.75f,0.25f,0.75f,0},
                                      {0,0,0,0,0,0}};
__device__ const int   UP_OFF[4] = {0,1,5,14};
__device__ const int   UP_S[4]   = {1,2,3,6};

__global__ __launch_bounds__(256) void pack_kernel(
        const float* __restrict__ convK, const float* __restrict__ convV,
        unsigned short* __restrict__ mk_b, unsigned short* __restrict__ mv_b) {
    int F = blockIdx.x * 256 + threadIdx.x;
    const int NMK = B_ * M_ * CK;   // 73728
    if (F < NMK) {
        int c = F & 255;
        int m = (F >> 8) % M_;
        int b = F / (M_ * 256);
        int t = m / 36, rem = m % 36, y = rem / 6, x = rem % 6;
        int si = c >> 6, co = c & 63;
        int s = UP_S[si], off = UP_OFF[si];
        const float* base = convK + (size_t)((t*B_ + b)*50) * 64 + co;
        int py0 = UP_P0[si][y], py1 = UP_P1[si][y];
        int px0 = UP_P0[si][x], px1 = UP_P1[si][x];
        float wy0 = UP_W0[si][y], wy1 = UP_W1[si][y];
        float wx0 = UP_W0[si][x], wx1 = UP_W1[si][x];
        float v = wy0 * (wx0 * base[(off + py0*s + px0)*64] + wx1 * base[(off + py0*s + px1)*64])
                + wy1 * (wx0 * base[(off + py1*s + px0)*64] + wx1 * base[(off + py1*s + px1)*64]);
        mk_b[F] = f2bf(v);
    } else {
        int G = F - NMK;
        int mp = G % MP;
        int cv = (G / MP) % CV;
        int b = G / (MP * CV);
        if (mp >= M_) { mv_b[G] = 0; return; }
        int m = mp;
        int t = m / 36, rem = m % 36, y = rem / 6, x = rem % 6;
        int si = cv >> 7, co = cv & 127;
        int s = UP_S[si], off = UP_OFF[si];
        const float* base = convV + (size_t)((t*B_ + b)*50) * 128 + co;
        int py0 = UP_P0[si][y], py1 = UP_P1[si][y];
        int px0 = UP_P0[si][x], px1 = UP_P1[si][x];
        float wy0 = UP_W0[si][y], wy1 = UP_W1[si][y];
        float wx0 = UP_W0[si][x], wx1 = UP_W1[si][x];
        float v = wy0 * (wx0 * base[(off + py0*s + px0)*128] + wx1 * base[(off + py0*s + px1)*128])
                + wy1 * (wx0 * base[(off + py1*s + px0)*128] + wx1 * base[(off + py1*s + px1)*128]);
        mv_b[G] = f2bf(v);
    }
}

// ---------------------------------------------------------------------------
// K4: fused attention per 64-pixel tile + qv passthrough copy.
//  phase A: S = mk(144x256) @ qk(256x64)  (mfma 16x16x32 bf16)
//  softmax over all 144 rows within each wave (wave owns 16 columns)
//  P -> LDS (bf16, B-operand layout), phase B: mem = mv(512x160) @ P(160x64)
// MFMA layouts (verified, learn_hip m89/m91/m120):
//  A: A[m=lane&15][k=quad*8+j]; B: B[k=quad*8+j][n=lane&15];
//  C/D: col=lane&15, row=quad*4+reg.
// ---------------------------------------------------------------------------
__global__ __launch_bounds__(256) void attn_kernel(
        const float* __restrict__ qk, const float* __restrict__ qv,
        const unsigned short* __restrict__ mk_b, const unsigned short* __restrict__ mv_b,
        float* __restrict__ out) {
    // qk tile transposed: [n(64)][c(256)] bf16, row padded to 264 (bank spread)
    __shared__ __align__(16) unsigned short qk_s[64 * 264];
    // P: [n(64)][m(160)] bf16, row padded to 168 (16B-aligned rows, bank spread)
    __shared__ __align__(16) unsigned short p_s[64 * 168];

    int blk = blockIdx.x;
    int b = blk / 144;
    int n0 = (blk % 144) * 64;
    int tid = threadIdx.x;

    // ---- stage qk[b, :, n0:n0+64] -> LDS transposed bf16 ----
    {
        int nn = tid & 63, cq = tid >> 6;
        const float* qb = qk + (size_t)b * CK * NPIX + n0 + nn;
        for (int k = 0; k < 32; ++k) {
            int c0 = 2 * (cq + 4*k);
            float v0 = qb[(size_t)c0 * NPIX];
            float v1 = qb[(size_t)(c0 + 1) * NPIX];
            unsigned int pk = (unsigned int)f2bf(v0) | ((unsigned int)f2bf(v1) << 16);
            *reinterpret_cast<unsigned int*>(&qk_s[nn*264 + c0]) = pk;
        }
    }
    __syncthreads();

    int w = tid >> 6, l = tid & 63;
    int nl = l & 15, q = l >> 4;

    // ---- phase A: S tile, wave w owns columns n0+w*16 .. +15 ----
    short8 bq[8];
    #pragma unroll
    for (int kt = 0; kt < 8; ++kt)
        bq[kt] = *reinterpret_cast<const short8*>(&qk_s[(w*16 + nl)*264 + kt*32 + q*8]);

    floatx4 sc[9];
    const unsigned short* mkb = mk_b + (size_t)b * M_ * CK + (size_t)nl * CK + q*8;
    #pragma unroll
    for (int mt = 0; mt < 9; ++mt) {
        floatx4 acc = {0.f, 0.f, 0.f, 0.f};
        const unsigned short* ar = mkb + (size_t)mt * 16 * CK;
        #pragma unroll
        for (int kt = 0; kt < 8; ++kt) {
            short8 a = *reinterpret_cast<const short8*>(ar + kt*32);
            acc = __builtin_amdgcn_mfma_f32_16x16x32_bf16(a, bq[kt], acc, 0, 0, 0);
        }
        sc[mt] = acc;
    }

    // ---- softmax over m (144 values per column n) ----
    float mx = -3.0e38f;
    #pragma unroll
    for (int mt = 0; mt < 9; ++mt)
        #pragma unroll
        for (int r = 0; r < 4; ++r) {
            float tv = sc[mt][r] * 0.0625f;   // Ck^-0.5
            sc[mt][r] = tv;
            mx = fmaxf(mx, tv);
        }
    mx = fmaxf(mx, __shfl_xor(mx, 16));
    mx = fmaxf(mx, __shfl_xor(mx, 32));
    float sum = 0.f;
    #pragma unroll
    for (int mt = 0; mt < 9; ++mt)
        #pragma unroll
        for (int r = 0; r < 4; ++r) {
            float e = __expf(sc[mt][r] - mx);
            sc[mt][r] = e;
            sum += e;
        }
    sum += __shfl_xor(sum, 16);
    sum += __shfl_xor(sum, 32);
    float inv = 1.0f / sum;

    unsigned short* pw = &p_s[(w*16 + nl)*168];
    #pragma unroll
    for (int mt = 0; mt < 9; ++mt)
        #pragma unroll
        for (int r = 0; r < 4; ++r)
            pw[mt*16 + q*4 + r] = f2bf(sc[mt][r] * inv);
    #pragma unroll
    for (int r = 0; r < 4; ++r) pw[M_ + q*4 + r] = 0;   // zero pad m=144..159
    __syncthreads();

    // ---- phase B: mem tile. wave w owns cv rows w*128..w*128+127, all 64 cols ----
    short8 bp[4][5];
    #pragma unroll
    for (int ns = 0; ns < 4; ++ns)
        #pragma unroll
        for (int kt = 0; kt < 5; ++kt)
            bp[ns][kt] = *reinterpret_cast<const short8*>(&p_s[(ns*16 + nl)*168 + kt*32 + q*8]);

    const unsigned short* mvb = mv_b + (size_t)b * CV * MP + (size_t)(w*128 + nl) * MP + q*8;
    float* ob = out + (size_t)(b*1024 + 512 + w*128 + q*4) * NPIX + n0 + nl;
    #pragma unroll
    for (int mt2 = 0; mt2 < 8; ++mt2) {
        short8 af[5];
        const unsigned short* ar = mvb + (size_t)mt2 * 16 * MP;
        #pragma unroll
        for (int kt = 0; kt < 5; ++kt)
            af[kt] = *reinterpret_cast<const short8*>(ar + kt*32);
        #pragma unroll
        for (int ns = 0; ns < 4; ++ns) {
            floatx4 acc = {0.f, 0.f, 0.f, 0.f};
            #pragma unroll
            for (int kt = 0; kt < 5; ++kt)
                acc = __builtin_amdgcn_mfma_f32_16x16x32_bf16(af[kt], bp[ns][kt], acc, 0, 0, 0);
            float* op = ob + (size_t)(mt2*16) * NPIX + ns*16;
            op[0]        = acc[0];
            op[NPIX]     = acc[1];
            op[2*NPIX]   = acc[2];
            op[3*NPIX]   = acc[3];
        }
    }

    // ---- fused qv passthrough: out[b, 0:512, n0:n0+64] = qv slice ----
    {
        int f4 = tid & 15, rr = tid >> 4;
        const float* qvb = qv + (size_t)b * CV * NPIX + n0 + f4*4;
        float* ob2 = out + (size_t)b * 1024 * NPIX + n0 + f4*4;
        for (int it = 0; it < 32; ++it) {
            int cvr = it*16 + rr;
            float4 v = *reinterpret_cast<const float4*>(qvb + (size_t)cvr * NPIX);
            *reinterpret_cast<float4*>(ob2 + (size_t)cvr * NPIX) = v;
        }
    }
}

// ---------------------------------------------------------------------------
extern "C" void kernel_launch(void* const* d_in, const int* in_sizes, int n_in,
                              void* d_out, int out_size, void* d_ws, size_t ws_size,
                              hipStream_t stream) {
    const float* keys  = (const float*)d_in[0];
    const float* vals  = (const float*)d_in[1];
    const float* qk    = (const float*)d_in[2];
    const float* qv    = (const float*)d_in[3];
    const float* key_w = (const float*)d_in[4];
    const float* key_b = (const float*)d_in[5];
    const float* val_w = (const float*)d_in[6];
    const float* val_b = (const float*)d_in[7];
    float* out = (float*)d_out;

    char* ws = (char*)d_ws;
    float* pooledK = (float*)(ws + 0);            // 102400 f32
    float* pooledV = (float*)(ws + 409600);       // 204800 f32
    float* convK   = (float*)(ws + 1228800);      // 25600 f32
    float* convV   = (float*)(ws + 1331200);      // 51200 f32
    unsigned short* mk_b = (unsigned short*)(ws + 1536000);   // 73728 bf16
    unsigned short* mv_b = (unsigned short*)(ws + 1683456);   // 163840 bf16

    hipLaunchKernelGGL(pool_kernel, dim3(T_*B_*(CK+CV)), dim3(256), 0, stream,
                       keys, vals, pooledK, pooledV);
    hipLaunchKernelGGL(conv_kernel, dim3((T_*B_*50*64 + T_*B_*50*128) / 4 / 64), dim3(256), 0, stream,
                       pooledK, pooledV, key_w, key_b, val_w, val_b, convK, convV);
    hipLaunchKernelGGL(pack_kernel, dim3((B_*M_*CK + B_*CV*MP) / 256), dim3(256), 0, stream,
                       convK, convV, mk_b, mv_b);
    hipLaunchKernelGGL(attn_kernel, dim3(B_ * (NPIX/64)), dim3(256), 0, stream,
                       qk, qv, mk_b, mv_b, out);
}

// Round 2
// 359.316 us; speedup vs baseline: 1.0254x; 1.0254x over previous
//
#include <hip/hip_runtime.h>
#include <hip/hip_bf16.h>

#define T_ 4
#define B_ 2
#define CK 256
#define CV 512
#define HH 96
#define WW 96
#define NPIX (HH*WW)   // 9216
#define M_ 144         // T_*6*6
#define MP 160         // M_ padded to multiple of 32 for K-loop

typedef __attribute__((ext_vector_type(8))) short short8;
typedef __attribute__((ext_vector_type(4))) float floatx4;

__device__ __forceinline__ unsigned short f2bf(float f) {
    unsigned int u = __float_as_uint(f);
    u += 0x7FFFu + ((u >> 16) & 1u);   // RNE
    return (unsigned short)(u >> 16);
}

// ---------------------------------------------------------------------------
// K1: pool [*,96,96] planes into 50 scale-position means (scales 1,2,3,6).
// One block (384 threads) per plane. Thread t: col-float4 g=t%24, row-base
// rb=t/24; 6 INDEPENDENT float4 loads (rows rb+16k, k=0..5) -> high MLP,
// fully coalesced. Single LDS tree reduction afterwards.
// Output layout: pooled[tb][pos(50)][c] (contiguous in c for conv).
// ---------------------------------------------------------------------------
__global__ __launch_bounds__(384) void pool_kernel(
        const float* __restrict__ keys, const float* __restrict__ vals,
        float* __restrict__ pooledK, float* __restrict__ pooledV) {
    int pid = blockIdx.x;
    const float* src; float* dstbase; int Cstride;
    if (pid < T_*B_*CK) {
        int tb = pid / CK, c = pid % CK;
        src = keys + (size_t)pid * NPIX;
        dstbase = pooledK + (size_t)tb * 50 * CK + c;
        Cstride = CK;
    } else {
        int p = pid - T_*B_*CK;
        int tb = p / CV, c = p % CV;
        src = vals + (size_t)p * NPIX;
        dstbase = pooledV + (size_t)tb * 50 * CV + c;
        Cstride = CV;
    }

    int t = threadIdx.x;
    int g = t % 24, rb = t / 24;
    const float* p0 = src + rb*WW + g*4;

    float4 v[6];
    #pragma unroll
    for (int k = 0; k < 6; ++k)
        v[k] = *reinterpret_cast<const float4*>(p0 + (size_t)k*16*WW);

    __shared__ float lds[6*16*24];
    #pragma unroll
    for (int k = 0; k < 6; ++k)
        lds[(k*16 + rb)*24 + g] = v[k].x + v[k].y + v[k].z + v[k].w;
    __syncthreads();

    __shared__ float part[144];
    if (t < 144) {
        int cidx = t >> 2, p = t & 3;        // cell cidx: k=cidx/6 (row-cell), cc=cidx%6
        int k = cidx / 6, cc = cidx % 6;
        float a = 0.f;
        #pragma unroll
        for (int r2 = 0; r2 < 16; ++r2)
            a += lds[(k*16 + r2)*24 + cc*4 + p];
        part[t] = a;
    }
    __syncthreads();
    __shared__ float cm[36];
    if (t < 36)
        cm[t] = (part[t*4] + part[t*4+1] + part[t*4+2] + part[t*4+3]) * (1.0f/256.0f);
    __syncthreads();

    if (t < 50) {
        float val;
        if (t == 0) {                        // s=1
            float a = 0.f;
            #pragma unroll
            for (int i = 0; i < 36; ++i) a += cm[i];
            val = a * (1.0f/36.0f);
        } else if (t < 5) {                  // s=2: 3x3 groups of cells
            int k = t - 1; int i = k >> 1, j = k & 1;
            float a = 0.f;
            for (int di = 0; di < 3; ++di)
                for (int dj = 0; dj < 3; ++dj) a += cm[(i*3+di)*6 + (j*3+dj)];
            val = a * (1.0f/9.0f);
        } else if (t < 14) {                 // s=3: 2x2 groups
            int k = t - 5; int i = k / 3, j = k % 3;
            float a = 0.f;
            for (int di = 0; di < 2; ++di)
                for (int dj = 0; dj < 2; ++dj) a += cm[(i*2+di)*6 + (j*2+dj)];
            val = a * 0.25f;
        } else {                             // s=6
            val = cm[t - 14];
        }
        dstbase[t * Cstride] = val;
    }
}

// ---------------------------------------------------------------------------
// K2: per-frame/per-scale 1x1 conv + bias + relu. One wave per output elem.
// pooled layout [tb][pos][c] -> both weight row and pooled row COALESCED.
// convK layout [tb][pos(50)][co(64)], convV [tb][pos][co(128)].
// ---------------------------------------------------------------------------
__global__ __launch_bounds__(256) void conv_kernel(
        const float* __restrict__ pooledK, const float* __restrict__ pooledV,
        const float* __restrict__ key_w, const float* __restrict__ key_b,
        const float* __restrict__ val_w, const float* __restrict__ val_b,
        float* __restrict__ convK, float* __restrict__ convV) {
    int gid = blockIdx.x * 4 + (threadIdx.x >> 6);
    int lane = threadIdx.x & 63;
    const int EK = T_*B_*50*64;   // 25600
    float acc = 0.f;
    if (gid < EK) {
        int co = gid & 63;
        int pos = (gid >> 6) % 50;
        int tb = gid / (64*50);
        int b = tb & 1, t = tb >> 1;
        int si = (pos == 0) ? 0 : (pos < 5 ? 1 : (pos < 14 ? 2 : 3));
        const float* wrow = key_w + (size_t)((t*4 + si)*64 + co) * CK;
        const float* prow = pooledK + (size_t)(tb*50 + pos) * CK;
        #pragma unroll
        for (int k = 0; k < 4; ++k) {
            int c = lane + 64*k;
            acc += wrow[c] * prow[c];
        }
        #pragma unroll
        for (int m = 1; m < 64; m <<= 1) acc += __shfl_xor(acc, m);
        if (lane == 0) convK[gid] = fmaxf(acc + key_b[(t*4 + si)*64 + co], 0.f);
    } else {
        int g2 = gid - EK;
        int co = g2 & 127;
        int pos = (g2 >> 7) % 50;
        int tb = g2 / (128*50);
        int b = tb & 1, t = tb >> 1;
        int si = (pos == 0) ? 0 : (pos < 5 ? 1 : (pos < 14 ? 2 : 3));
        const float* wrow = val_w + (size_t)((t*4 + si)*128 + co) * CV;
        const float* prow = pooledV + (size_t)(tb*50 + pos) * CV;
        #pragma unroll
        for (int k = 0; k < 8; ++k) {
            int c = lane + 64*k;
            acc += wrow[c] * prow[c];
        }
        #pragma unroll
        for (int m = 1; m < 64; m <<= 1) acc += __shfl_xor(acc, m);
        if (lane == 0) convV[g2] = fmaxf(acc + val_b[(t*4 + si)*128 + co], 0.f);
    }
}

// ---------------------------------------------------------------------------
// K3: bilinear upsample (align_corners=False, jax.image.resize semantics) +
// pack to bf16: mk [b][m=144][c=256], mv [b][cv=512][mp=160] (144..159 = 0).
// ---------------------------------------------------------------------------
__device__ const int   UP_P0[4][6] = {{0,0,0,0,0,0},{0,0,0,0,1,1},{0,0,0,1,1,2},{0,1,2,3,4,5}};
__device__ const int   UP_P1[4][6] = {{0,0,0,0,0,0},{0,0,1,1,1,1},{0,1,1,2,2,2},{0,1,2,3,4,5}};
__device__ const float UP_W0[4][6] = {{1,1,1,1,1,1},
                                      {1,1,0.66666669f,0.33333334f,1,1},
                                      {1,0.75f,0.25f,0.75f,0.25f,1},
                                      {1,1,1,1,1,1}};
__device__ const float UP_W1[4][6] = {{0,0,0,0,0,0},
                                      {0,0,0.33333334f,0.66666669f,0,0},
                                      {0,0.25f,0.75f,0.25f,0.75f,0},
                                      {0,0,0,0,0,0}};
__device__ const int   UP_OFF[4] = {0,1,5,14};
__device__ const int   UP_S[4]   = {1,2,3,6};

__global__ __launch_bounds__(256) void pack_kernel(
        const float* __restrict__ convK, const float* __restrict__ convV,
        unsigned short* __restrict__ mk_b, unsigned short* __restrict__ mv_b) {
    int F = blockIdx.x * 256 + threadIdx.x;
    const int NMK = B_ * M_ * CK;   // 73728
    if (F < NMK) {
        int c = F & 255;
        int m = (F >> 8) % M_;
        int b = F / (M_ * 256);
        int t = m / 36, rem = m % 36, y = rem / 6, x = rem % 6;
        int si = c >> 6, co = c & 63;
        int s = UP_S[si], off = UP_OFF[si];
        const float* base = convK + (size_t)((t*B_ + b)*50) * 64 + co;
        int py0 = UP_P0[si][y], py1 = UP_P1[si][y];
        int px0 = UP_P0[si][x], px1 = UP_P1[si][x];
        float wy0 = UP_W0[si][y], wy1 = UP_W1[si][y];
        float wx0 = UP_W0[si][x], wx1 = UP_W1[si][x];
        float v = wy0 * (wx0 * base[(off + py0*s + px0)*64] + wx1 * base[(off + py0*s + px1)*64])
                + wy1 * (wx0 * base[(off + py1*s + px0)*64] + wx1 * base[(off + py1*s + px1)*64]);
        mk_b[F] = f2bf(v);
    } else {
        int G = F - NMK;
        int mp = G % MP;
        int cv = (G / MP) % CV;
        int b = G / (MP * CV);
        if (mp >= M_) { mv_b[G] = 0; return; }
        int m = mp;
        int t = m / 36, rem = m % 36, y = rem / 6, x = rem % 6;
        int si = cv >> 7, co = cv & 127;
        int s = UP_S[si], off = UP_OFF[si];
        const float* base = convV + (size_t)((t*B_ + b)*50) * 128 + co;
        int py0 = UP_P0[si][y], py1 = UP_P1[si][y];
        int px0 = UP_P0[si][x], px1 = UP_P1[si][x];
        float wy0 = UP_W0[si][y], wy1 = UP_W1[si][y];
        float wx0 = UP_W0[si][x], wx1 = UP_W1[si][x];
        float v = wy0 * (wx0 * base[(off + py0*s + px0)*128] + wx1 * base[(off + py0*s + px1)*128])
                + wy1 * (wx0 * base[(off + py1*s + px0)*128] + wx1 * base[(off + py1*s + px1)*128]);
        mv_b[G] = f2bf(v);
    }
}

// ---------------------------------------------------------------------------
// K4: fused attention per 64-pixel tile (qv passthrough moved to K5).
//  phase A: S = mk(144x256) @ qk(256x64)  (mfma 16x16x32 bf16)
//  softmax over all 144 rows within each wave (wave owns 16 columns)
//  P -> LDS (bf16, B-operand layout), phase B: mem = mv(512x160) @ P(160x64)
// qk staging vectorized: float4 along pixel dim, 16 independent loads/thread.
// ---------------------------------------------------------------------------
__global__ __launch_bounds__(256) void attn_kernel(
        const float* __restrict__ qk,
        const unsigned short* __restrict__ mk_b, const unsigned short* __restrict__ mv_b,
        float* __restrict__ out) {
    __shared__ __align__(16) unsigned short qk_s[64 * 264];
    __shared__ __align__(16) unsigned short p_s[64 * 168];

    int blk = blockIdx.x;
    int b = blk / 144;
    int n0 = (blk % 144) * 64;
    int tid = threadIdx.x;

    // ---- stage qk[b, :, n0:n0+64] -> LDS transposed bf16 ----
    {
        int px = (tid & 15) * 4;
        int c0 = tid >> 4;   // 0..15
        const float* qb = qk + (size_t)b * CK * NPIX + n0 + px;
        #pragma unroll
        for (int k = 0; k < 16; ++k) {
            int c = c0 + 16*k;
            float4 v = *reinterpret_cast<const float4*>(qb + (size_t)c * NPIX);
            qk_s[(px+0)*264 + c] = f2bf(v.x);
            qk_s[(px+1)*264 + c] = f2bf(v.y);
            qk_s[(px+2)*264 + c] = f2bf(v.z);
            qk_s[(px+3)*264 + c] = f2bf(v.w);
        }
    }
    __syncthreads();

    int w = tid >> 6, l = tid & 63;
    int nl = l & 15, q = l >> 4;

    // ---- phase A: S tile, wave w owns columns n0+w*16 .. +15 ----
    short8 bq[8];
    #pragma unroll
    for (int kt = 0; kt < 8; ++kt)
        bq[kt] = *reinterpret_cast<const short8*>(&qk_s[(w*16 + nl)*264 + kt*32 + q*8]);

    floatx4 sc[9];
    const unsigned short* mkb = mk_b + (size_t)b * M_ * CK + (size_t)nl * CK + q*8;
    #pragma unroll
    for (int mt = 0; mt < 9; ++mt) {
        floatx4 acc = {0.f, 0.f, 0.f, 0.f};
        const unsigned short* ar = mkb + (size_t)mt * 16 * CK;
        #pragma unroll
        for (int kt = 0; kt < 8; ++kt) {
            short8 a = *reinterpret_cast<const short8*>(ar + kt*32);
            acc = __builtin_amdgcn_mfma_f32_16x16x32_bf16(a, bq[kt], acc, 0, 0, 0);
        }
        sc[mt] = acc;
    }

    // ---- softmax over m (144 values per column n) ----
    float mx = -3.0e38f;
    #pragma unroll
    for (int mt = 0; mt < 9; ++mt)
        #pragma unroll
        for (int r = 0; r < 4; ++r) {
            float tv = sc[mt][r] * 0.0625f;   // Ck^-0.5
            sc[mt][r] = tv;
            mx = fmaxf(mx, tv);
        }
    mx = fmaxf(mx, __shfl_xor(mx, 16));
    mx = fmaxf(mx, __shfl_xor(mx, 32));
    float sum = 0.f;
    #pragma unroll
    for (int mt = 0; mt < 9; ++mt)
        #pragma unroll
        for (int r = 0; r < 4; ++r) {
            float e = __expf(sc[mt][r] - mx);
            sc[mt][r] = e;
            sum += e;
        }
    sum += __shfl_xor(sum, 16);
    sum += __shfl_xor(sum, 32);
    float inv = 1.0f / sum;

    unsigned short* pw = &p_s[(w*16 + nl)*168];
    #pragma unroll
    for (int mt = 0; mt < 9; ++mt)
        #pragma unroll
        for (int r = 0; r < 4; ++r)
            pw[mt*16 + q*4 + r] = f2bf(sc[mt][r] * inv);
    #pragma unroll
    for (int r = 0; r < 4; ++r) pw[M_ + q*4 + r] = 0;   // zero pad m=144..159
    __syncthreads();

    // ---- phase B: mem tile. wave w owns cv rows w*128..w*128+127 ----
    short8 bp[4][5];
    #pragma unroll
    for (int ns = 0; ns < 4; ++ns)
        #pragma unroll
        for (int kt = 0; kt < 5; ++kt)
            bp[ns][kt] = *reinterpret_cast<const short8*>(&p_s[(ns*16 + nl)*168 + kt*32 + q*8]);

    const unsigned short* mvb = mv_b + (size_t)b * CV * MP + (size_t)(w*128 + nl) * MP + q*8;
    float* ob = out + (size_t)(b*1024 + 512 + w*128 + q*4) * NPIX + n0 + nl;
    #pragma unroll
    for (int mt2 = 0; mt2 < 8; ++mt2) {
        short8 af[5];
        const unsigned short* ar = mvb + (size_t)mt2 * 16 * MP;
        #pragma unroll
        for (int kt = 0; kt < 5; ++kt)
            af[kt] = *reinterpret_cast<const short8*>(ar + kt*32);
        #pragma unroll
        for (int ns = 0; ns < 4; ++ns) {
            floatx4 acc = {0.f, 0.f, 0.f, 0.f};
            #pragma unroll
            for (int kt = 0; kt < 5; ++kt)
                acc = __builtin_amdgcn_mfma_f32_16x16x32_bf16(af[kt], bp[ns][kt], acc, 0, 0, 0);
            float* op = ob + (size_t)(mt2*16) * NPIX + ns*16;
            op[0]        = acc[0];
            op[NPIX]     = acc[1];
            op[2*NPIX]   = acc[2];
            op[3*NPIX]   = acc[3];
        }
    }
}

// ---------------------------------------------------------------------------
// K5: qv passthrough: out[b, 0:512, :] = qv[b]. Pure streaming float4 copy.
// ---------------------------------------------------------------------------
__global__ __launch_bounds__(256) void qvcopy_kernel(
        const float* __restrict__ qv, float* __restrict__ out) {
    size_t off = ((size_t)blockIdx.x * 256 + threadIdx.x) * 4;
    size_t b1 = (size_t)CV * NPIX;           // elements per batch
    size_t dst = off + (off >= b1 ? b1 : 0); // batch 1 shifts by 512*NPIX
    float4 v = *reinterpret_cast<const float4*>(qv + off);
    *reinterpret_cast<float4*>(out + dst) = v;
}

// ---------------------------------------------------------------------------
extern "C" void kernel_launch(void* const* d_in, const int* in_sizes, int n_in,
                              void* d_out, int out_size, void* d_ws, size_t ws_size,
                              hipStream_t stream) {
    const float* keys  = (const float*)d_in[0];
    const float* vals  = (const float*)d_in[1];
    const float* qk    = (const float*)d_in[2];
    const float* qv    = (const float*)d_in[3];
    const float* key_w = (const float*)d_in[4];
    const float* key_b = (const float*)d_in[5];
    const float* val_w = (const float*)d_in[6];
    const float* val_b = (const float*)d_in[7];
    float* out = (float*)d_out;

    char* ws = (char*)d_ws;
    float* pooledK = (float*)(ws + 0);            // 102400 f32
    float* pooledV = (float*)(ws + 409600);       // 204800 f32
    float* convK   = (float*)(ws + 1228800);      // 25600 f32
    float* convV   = (float*)(ws + 1331200);      // 51200 f32
    unsigned short* mk_b = (unsigned short*)(ws + 1536000);   // 73728 bf16
    unsigned short* mv_b = (unsigned short*)(ws + 1683456);   // 163840 bf16

    hipLaunchKernelGGL(pool_kernel, dim3(T_*B_*(CK+CV)), dim3(384), 0, stream,
                       keys, vals, pooledK, pooledV);
    hipLaunchKernelGGL(conv_kernel, dim3((T_*B_*50*64 + T_*B_*50*128) / 4 / 64), dim3(256), 0, stream,
                       pooledK, pooledV, key_w, key_b, val_w, val_b, convK, convV);
    hipLaunchKernelGGL(pack_kernel, dim3((B_*M_*CK + B_*CV*MP) / 256), dim3(256), 0, stream,
                       convK, convV, mk_b, mv_b);
    hipLaunchKernelGGL(attn_kernel, dim3(B_ * (NPIX/64)), dim3(256), 0, stream,
                       qk, mk_b, mv_b, out);
    hipLaunchKernelGGL(qvcopy_kernel, dim3(B_*CV*NPIX/4/256), dim3(256), 0, stream,
                       qv, out);
}